// Round 8
// baseline (547.645 us; speedup 1.0000x reference)
//
#include <hip/hip_runtime.h>
#include <hip/hip_bf16.h>

// MultiHeadCA bf16-MFMA pipeline. Transposed flash attention, QB=128,
// mask pre-packed into MFMA C-fragment order. B=4, T=2048, D=1024, NH=16.

#define D_MODEL 1024
#define NH      16
#define HEAD    64
#define BATCH   4
#define SEQ     2048
#define QB      128

typedef unsigned int   u32;
typedef unsigned short u16;
typedef __attribute__((ext_vector_type(8))) short s16x8;   // 8 bf16 (4 VGPRs)
typedef __attribute__((ext_vector_type(4))) float f32x4;   // MFMA C/D

__device__ __forceinline__ u16 tobf(float f) {   // RNE f32->bf16
    u32 u = __builtin_bit_cast(u32, f);
    return (u16)((u + 0x7fffu + ((u >> 16) & 1u)) >> 16);
}
__device__ __forceinline__ float frombf(u16 u) {
    return __builtin_bit_cast(float, (u32)u << 16);
}
__device__ __forceinline__ u32 pack_bf2(float a, float b) {
    return (u32)tobf(a) | ((u32)tobf(b) << 16);
}

__device__ __forceinline__ void gl_lds16(const void* g, void* l) {
    __builtin_amdgcn_global_load_lds(
        (const __attribute__((address_space(1))) u32*)g,
        (__attribute__((address_space(3))) u32*)l, 16, 0, 0);
}

// ---------------- cast f32 -> bf16 ----------------
__global__ __launch_bounds__(256) void cast_bf16(
    const float* __restrict__ in, u16* __restrict__ out, int n)
{
    int i = (blockIdx.x * 256 + threadIdx.x) * 4;
    if (i < n) {
        float4 v = *(const float4*)(in + i);
        ushort4 o = make_ushort4(tobf(v.x), tobf(v.y), tobf(v.z), tobf(v.w));
        *(ushort4*)(out + i) = o;
    }
}

// ---------------- mask f32 -> bf16 in MFMA C-frag tile order --------------
// tile (b, qt, kt): 16x16. elem (q=qt*16+q15, k=kt*16+quad*4+r) stored at
// tile_base + (quad*16+q15)*4 + r  -> attn lane l reads contiguous 8 B.
__global__ __launch_bounds__(256) void mask_prep(
    const float* __restrict__ mask, u16* __restrict__ mp)
{
    const size_t gt = (size_t)blockIdx.x * 256 + threadIdx.x; // < 4*128*128*64
    const int l = (int)(gt & 63);
    const size_t tile = gt >> 6;          // (b*128+qt)*128+kt
    const int kt = (int)(tile & 127);
    const size_t bq = tile >> 7;
    const int qt = (int)(bq & 127);
    const int b  = (int)(bq >> 7);
    const int q15 = l & 15, quad = l >> 4;
    const int q = qt*16 + q15;
    const int k = kt*16 + quad*4;
    float4 v = *(const float4*)&mask[((size_t)(b*SEQ + q))*SEQ + k];
    ushort4 o = make_ushort4(tobf(v.x), tobf(v.y), tobf(v.z), tobf(v.w));
    *(ushort4*)&mp[tile*256 + (size_t)l*4] = o;
}

// ---------------- W (KxN f32) -> W^T (NxK bf16) ----------------
__global__ __launch_bounds__(256) void transpose_cast(
    const float* __restrict__ W, u16* __restrict__ WT, int K, int N)
{
    __shared__ __align__(16) float tile[32][33];
    const int n0 = blockIdx.x * 32, k0 = blockIdx.y * 32;
    const int r = threadIdx.x >> 3, c4 = (threadIdx.x & 7) * 4;
    float4 v = *(const float4*)&W[(size_t)(k0 + r) * N + n0 + c4];
    tile[r][c4] = v.x; tile[r][c4+1] = v.y; tile[r][c4+2] = v.z; tile[r][c4+3] = v.w;
    __syncthreads();
    ushort4 o = make_ushort4(tobf(tile[c4+0][r]), tobf(tile[c4+1][r]),
                             tobf(tile[c4+2][r]), tobf(tile[c4+3][r]));
    *(ushort4*)&WT[(size_t)(n0 + r) * K + k0 + c4] = o;
}

// ---------------- m97-style GEMM: A(MxK bf16) @ Bt(NxK bf16)^T + bias -> C --
__device__ __forceinline__ void store_out(u16* p, float v)  { *p = tobf(v); }
__device__ __forceinline__ void store_out(float* p, float v){ *p = v; }

template <typename OT>
__global__ __launch_bounds__(256) void gemm_bt(
    const u16* __restrict__ A, const u16* __restrict__ Bt,
    const float* __restrict__ bias, OT* __restrict__ C,
    int N, int K, float out_scale)
{
    __shared__ __align__(16) u16 As[128 * 32];
    __shared__ __align__(16) u16 Bs[128 * 32];
    const int t = threadIdx.x;
    const int w = t >> 6, l = t & 63;
    const int lane15 = l & 15, quad = l >> 4;
    const int m0 = blockIdx.y * 128, n0 = blockIdx.x * 128;
    const int wm = (w >> 1) * 64, wn = (w & 1) * 64;
    const int lr = l >> 2, lk = (l & 3) * 8;

    f32x4 acc[4][4] = {};

    for (int k0 = 0; k0 < K; k0 += 32) {
        __syncthreads();
        #pragma unroll
        for (int i = 0; i < 2; ++i) {
            const int chunk = w * 2 + i;
            gl_lds16(A  + (size_t)(m0 + chunk*16 + lr) * K + k0 + lk,
                     As + chunk * 512);
            gl_lds16(Bt + (size_t)(n0 + chunk*16 + lr) * K + k0 + lk,
                     Bs + chunk * 512);
        }
        __syncthreads();
        s16x8 af[4], bfr[4];
        #pragma unroll
        for (int i = 0; i < 4; ++i)
            af[i] = *(const s16x8*)&As[(wm + i*16 + lane15) * 32 + quad * 8];
        #pragma unroll
        for (int j = 0; j < 4; ++j)
            bfr[j] = *(const s16x8*)&Bs[(wn + j*16 + lane15) * 32 + quad * 8];
        #pragma unroll
        for (int i = 0; i < 4; ++i)
            #pragma unroll
            for (int j = 0; j < 4; ++j)
                acc[i][j] = __builtin_amdgcn_mfma_f32_16x16x32_bf16(
                    af[i], bfr[j], acc[i][j], 0, 0, 0);
    }
    #pragma unroll
    for (int j = 0; j < 4; ++j) {
        const int col = n0 + wn + j*16 + lane15;
        const float bv = bias[col];
        #pragma unroll
        for (int i = 0; i < 4; ++i)
            #pragma unroll
            for (int r = 0; r < 4; ++r) {
                const int row = m0 + wm + i*16 + quad*4 + r;
                store_out(C + (size_t)row * N + col, (acc[i][j][r] + bv) * out_scale);
            }
    }
}

// ---------------- V head transpose: kv[b,t,h*128+64+d] -> vt[(bh*64+d)*T+t] -
__global__ __launch_bounds__(256) void v_transpose(
    const u16* __restrict__ kvb, u16* __restrict__ vt)
{
    __shared__ __align__(16) u16 tile[64][72];
    const int t  = threadIdx.x;
    const int t0 = blockIdx.x * 64;
    const int bh = blockIdx.y;
    const int b = bh >> 4, h = bh & 15;
    const int r = t >> 2, c = (t & 3) * 16;
    const u16* g = kvb + (size_t)(b*SEQ + t0 + r) * (2*D_MODEL) + h*128 + 64 + c;
    *(uint4*)&tile[r][c]     = *(const uint4*)g;
    *(uint4*)&tile[r][c + 8] = *(const uint4*)(g + 8);
    __syncthreads();
    u16 buf[16];
    #pragma unroll
    for (int i = 0; i < 16; ++i) buf[i] = tile[c + i][r];
    u16* o = vt + (size_t)(bh*64 + r) * SEQ + t0 + c;
    *(uint4*)o       = *(uint4*)&buf[0];
    *(uint4*)(o + 8) = *(uint4*)&buf[8];
}

// ---------------- Transposed MFMA flash attention, QB=128 ----------------
// 4 waves x 32 q-rows (2 frag sets of 16). K-tile 64. K/V frags read once
// per wave-iter, reused across both sets. Mask: direct coalesced global load
// from pre-packed C-frag-order buffer. No-max softmax (bounded scores).
__global__ __launch_bounds__(256) void attn_mfma(
    const u16* __restrict__ qb, const u16* __restrict__ kvb,
    const u16* __restrict__ vt, const u16* __restrict__ mp,
    u16* __restrict__ resb)
{
    __shared__ __align__(16) u16 sm[2*64*72 + 4*32*72];  // Ks|Vs then Ps
    u16* const Ks = sm;                 // [64][72]
    u16* const Vs = sm + 64*72;         // [64][72]
    u16* const Ps = sm + 2*64*72;       // [4][32][72]
    const int t = threadIdx.x;
    const int w = t >> 6, l = t & 63;
    const int lane15 = l & 15, quad = l >> 4;
    const int h  = blockIdx.x;          // h fastest: adjacent blocks share mask
    const int q0 = blockIdx.y * QB;
    const int b  = blockIdx.z;
    const int bh = b * NH + h;
    const int sr = t >> 2, sc = (t & 3) * 16;

    // Q fragments for the wave's 2 q-sets (Q/8 pre-scaled)
    s16x8 aq0[2], aq1[2];
    #pragma unroll
    for (int s = 0; s < 2; ++s) {
        const u16* qrow = qb + (size_t)(b*SEQ + q0 + w*32 + s*16 + lane15) * D_MODEL + h*HEAD;
        aq0[s] = *(const s16x8*)(qrow + quad*8);
        aq1[s] = *(const s16x8*)(qrow + 32 + quad*8);
    }
    // mask tile base per set: tiles are 256 u16; qt = q0/16 + w*2 + s
    const u16* mrow[2];
    #pragma unroll
    for (int s = 0; s < 2; ++s)
        mrow[s] = mp + (((size_t)b*128 + (q0>>4) + w*2 + s) * 128) * 256 + (size_t)l*4;

    f32x4 o_acc[2][4] = {};
    float l_i[2] = {0.f, 0.f};

    for (int k0 = 0; k0 < SEQ; k0 += 64) {
        __syncthreads();
        {   // stage K [k][d], V^T [d][k]
            const u16* kg = kvb + (size_t)(b*SEQ + k0 + sr) * (2*D_MODEL) + h*128 + sc;
            *(uint4*)&Ks[sr*72 + sc]     = *(const uint4*)kg;
            *(uint4*)&Ks[sr*72 + sc + 8] = *(const uint4*)(kg + 8);
            const u16* vg = vt + (size_t)(bh*64 + sr) * SEQ + k0 + sc;
            *(uint4*)&Vs[sr*72 + sc]     = *(const uint4*)vg;
            *(uint4*)&Vs[sr*72 + sc + 8] = *(const uint4*)(vg + 8);
        }
        __syncthreads();

        // K fragments once, reused for both q-sets
        s16x8 kf[4][2];
        #pragma unroll
        for (int nt = 0; nt < 4; ++nt) {
            kf[nt][0] = *(const s16x8*)&Ks[(nt*16 + lane15)*72 + quad*8];
            kf[nt][1] = *(const s16x8*)&Ks[(nt*16 + lane15)*72 + 32 + quad*8];
        }

        #pragma unroll
        for (int s = 0; s < 2; ++s) {
            // S^T tile: C-init = mask (coalesced 8B load per nt)
            f32x4 sv[4];
            #pragma unroll
            for (int nt = 0; nt < 4; ++nt) {
                ushort4 m4 = *(const ushort4*)(mrow[s] + ((size_t)(k0>>4) + nt) * 256);
                sv[nt][0] = frombf(m4.x); sv[nt][1] = frombf(m4.y);
                sv[nt][2] = frombf(m4.z); sv[nt][3] = frombf(m4.w);
                sv[nt] = __builtin_amdgcn_mfma_f32_16x16x32_bf16(kf[nt][0], aq0[s], sv[nt], 0, 0, 0);
                sv[nt] = __builtin_amdgcn_mfma_f32_16x16x32_bf16(kf[nt][1], aq1[s], sv[nt], 0, 0, 0);
            }
            // no-max softmax numerator
            float rs = 0.f;
            #pragma unroll
            for (int nt = 0; nt < 4; ++nt)
                #pragma unroll
                for (int r = 0; r < 4; ++r) {
                    float p = __expf(sv[nt][r]);
                    sv[nt][r] = p;
                    rs += p;
                }
            rs += __shfl_xor(rs, 16);
            rs += __shfl_xor(rs, 32);
            l_i[s] += rs;
            // P -> per-wave LDS [q-local][k]
            u16* prow = &Ps[(w*32 + s*16 + lane15)*72];
            #pragma unroll
            for (int nt = 0; nt < 4; ++nt) {
                uint2 pv = make_uint2(pack_bf2(sv[nt][0], sv[nt][1]),
                                      pack_bf2(sv[nt][2], sv[nt][3]));
                *(uint2*)&prow[nt*16 + quad*4] = pv;
            }
        }

        // PV: O^T += V^T . P^T
        #pragma unroll
        for (int s = 0; s < 2; ++s) {
            const u16* prow = &Ps[(w*32 + s*16 + lane15)*72];
            s16x8 pf0 = *(const s16x8*)&prow[quad*8];
            s16x8 pf1 = *(const s16x8*)&prow[32 + quad*8];
            #pragma unroll
            for (int dt = 0; dt < 4; ++dt) {
                s16x8 vf0 = *(const s16x8*)&Vs[(dt*16 + lane15)*72 + quad*8];
                s16x8 vf1 = *(const s16x8*)&Vs[(dt*16 + lane15)*72 + 32 + quad*8];
                o_acc[s][dt] = __builtin_amdgcn_mfma_f32_16x16x32_bf16(vf0, pf0, o_acc[s][dt], 0, 0, 0);
                o_acc[s][dt] = __builtin_amdgcn_mfma_f32_16x16x32_bf16(vf1, pf1, o_acc[s][dt], 0, 0, 0);
            }
        }
    }

    // Epilogue: O^T (col=q, row=d) -> LDS transpose (reuse Ks+Vs: 128x72) -> store
    __syncthreads();
    #pragma unroll
    for (int s = 0; s < 2; ++s) {
        const float inv = 1.f / l_i[s];
        u16* orow = &sm[(w*32 + s*16 + lane15)*72];
        #pragma unroll
        for (int dt = 0; dt < 4; ++dt) {
            uint2 ov = make_uint2(pack_bf2(o_acc[s][dt][0]*inv, o_acc[s][dt][1]*inv),
                                  pack_bf2(o_acc[s][dt][2]*inv, o_acc[s][dt][3]*inv));
            *(uint2*)&orow[dt*16 + quad*4] = ov;
        }
    }
    __syncthreads();
    {
        const int tr = t >> 1, tc = (t & 1) * 32;
        u16* o = resb + (size_t)(b*SEQ + q0 + tr) * D_MODEL + h*HEAD + tc;
        #pragma unroll
        for (int j = 0; j < 4; ++j)
            *(uint4*)(o + j*8) = *(const uint4*)&sm[tr*72 + tc + j*8];
    }
}

extern "C" void kernel_launch(void* const* d_in, const int* in_sizes, int n_in,
                              void* d_out, int out_size, void* d_ws, size_t ws_size,
                              hipStream_t stream) {
    const float* x_enc = (const float*)d_in[0];
    const float* x_dec = (const float*)d_in[1];
    const float* mask  = (const float*)d_in[2];
    const float* Wq    = (const float*)d_in[3];
    const float* bq    = (const float*)d_in[4];
    const float* Wkv   = (const float*)d_in[5];
    const float* bkv   = (const float*)d_in[6];
    const float* Wo    = (const float*)d_in[7];
    const float* bo    = (const float*)d_in[8];
    float* out = (float*)d_out;

    const int M = BATCH * SEQ;  // 8192
    u16* xe   = (u16*)d_ws;                       // 8192x1024 (16.8 MB)
    u16* xd   = xe   + (size_t)M * D_MODEL;       // 8192x1024 (16.8 MB)
    u16* wqT  = xd   + (size_t)M * D_MODEL;       // 1024x1024
    u16* wkvT = wqT  + (size_t)D_MODEL * D_MODEL; // 2048x1024
    u16* woT  = wkvT + (size_t)2*D_MODEL*D_MODEL; // 1024x1024
    u16* qbuf = woT  + (size_t)D_MODEL * D_MODEL; // 8192x1024 (holds Q/8)
    u16* kvb  = qbuf + (size_t)M * D_MODEL;       // 8192x2048
    u16* vtb  = kvb  + (size_t)M * 2 * D_MODEL;   // 64x64x2048
    u16* resb = vtb  + (size_t)BATCH*NH*HEAD*SEQ; // 8192x1024
    u16* mpk  = xe;   // mask C-frag buffer (33.6 MB) aliases xe+xd after GEMMs

    const int NX = M * D_MODEL;  // 8388608
    cast_bf16<<<NX/1024, 256, 0, stream>>>(x_enc, xe, NX);
    cast_bf16<<<NX/1024, 256, 0, stream>>>(x_dec, xd, NX);
    transpose_cast<<<dim3(D_MODEL/32, D_MODEL/32), 256, 0, stream>>>(Wq,  wqT,  D_MODEL, D_MODEL);
    transpose_cast<<<dim3(2*D_MODEL/32, D_MODEL/32), 256, 0, stream>>>(Wkv, wkvT, D_MODEL, 2*D_MODEL);
    transpose_cast<<<dim3(D_MODEL/32, D_MODEL/32), 256, 0, stream>>>(Wo,  woT,  D_MODEL, D_MODEL);

    gemm_bt<u16><<<dim3(2*D_MODEL/128, M/128), 256, 0, stream>>>(
        xe, wkvT, bkv, kvb, 2*D_MODEL, D_MODEL, 1.0f);
    gemm_bt<u16><<<dim3(D_MODEL/128, M/128), 256, 0, stream>>>(
        xd, wqT, bq, qbuf, D_MODEL, D_MODEL, 0.125f);   // fold 1/sqrt(HEAD)
    // xe/xd dead now; pack mask into their space
    mask_prep<<<(BATCH*128*128*64)/256, 256, 0, stream>>>(mask, mpk);
    v_transpose<<<dim3(SEQ/64, BATCH*NH), 256, 0, stream>>>(kvb, vtb);
    attn_mfma<<<dim3(NH, SEQ/QB, BATCH), 256, 0, stream>>>(
        qbuf, kvb, vtb, mpk, resb);
    gemm_bt<float><<<dim3(D_MODEL/128, M/128), 256, 0, stream>>>(
        resb, woT, bo, out, D_MODEL, D_MODEL, 1.0f);
}

// Round 9
// 441.227 us; speedup vs baseline: 1.2412x; 1.2412x over previous
//
#include <hip/hip_runtime.h>
#include <hip/hip_bf16.h>

// MultiHeadCA bf16-MFMA pipeline. Transposed flash attention, QB=128,
// async double-buffered K/V staging (global_load_lds), mask reg-prefetch.
// B=4, T=2048, D=1024, NH=16, HEAD=64.

#define D_MODEL 1024
#define NH      16
#define HEAD    64
#define BATCH   4
#define SEQ     2048
#define QB      128

typedef unsigned int   u32;
typedef unsigned short u16;
typedef __attribute__((ext_vector_type(8))) short s16x8;   // 8 bf16 (4 VGPRs)
typedef __attribute__((ext_vector_type(4))) float f32x4;   // MFMA C/D

__device__ __forceinline__ u16 tobf(float f) {   // RNE f32->bf16
    u32 u = __builtin_bit_cast(u32, f);
    return (u16)((u + 0x7fffu + ((u >> 16) & 1u)) >> 16);
}
__device__ __forceinline__ float frombf(u16 u) {
    return __builtin_bit_cast(float, (u32)u << 16);
}
__device__ __forceinline__ u32 pack_bf2(float a, float b) {
    return (u32)tobf(a) | ((u32)tobf(b) << 16);
}

__device__ __forceinline__ void gl_lds16(const void* g, void* l) {
    __builtin_amdgcn_global_load_lds(
        (const __attribute__((address_space(1))) u32*)g,
        (__attribute__((address_space(3))) u32*)l, 16, 0, 0);
}

// ---------------- cast f32 -> bf16 ----------------
__global__ __launch_bounds__(256) void cast_bf16(
    const float* __restrict__ in, u16* __restrict__ out, int n)
{
    int i = (blockIdx.x * 256 + threadIdx.x) * 4;
    if (i < n) {
        float4 v = *(const float4*)(in + i);
        ushort4 o = make_ushort4(tobf(v.x), tobf(v.y), tobf(v.z), tobf(v.w));
        *(ushort4*)(out + i) = o;
    }
}

// ---------------- mask f32 -> bf16 in MFMA C-frag tile order --------------
// tile (b, qt, kt): 16x16. elem (q=qt*16+q15, k=kt*16+quad*4+r) stored at
// tile_base + (quad*16+q15)*4 + r  -> attn lane l reads contiguous 8 B.
__global__ __launch_bounds__(256) void mask_prep(
    const float* __restrict__ mask, u16* __restrict__ mp)
{
    const size_t gt = (size_t)blockIdx.x * 256 + threadIdx.x; // < 4*128*128*64
    const int l = (int)(gt & 63);
    const size_t tile = gt >> 6;          // (b*128+qt)*128+kt
    const int kt = (int)(tile & 127);
    const size_t bq = tile >> 7;
    const int qt = (int)(bq & 127);
    const int b  = (int)(bq >> 7);
    const int q15 = l & 15, quad = l >> 4;
    const int q = qt*16 + q15;
    const int k = kt*16 + quad*4;
    float4 v = *(const float4*)&mask[((size_t)(b*SEQ + q))*SEQ + k];
    ushort4 o = make_ushort4(tobf(v.x), tobf(v.y), tobf(v.z), tobf(v.w));
    *(ushort4*)&mp[tile*256 + (size_t)l*4] = o;
}

// ---------------- W (KxN f32) -> W^T (NxK bf16) ----------------
__global__ __launch_bounds__(256) void transpose_cast(
    const float* __restrict__ W, u16* __restrict__ WT, int K, int N)
{
    __shared__ __align__(16) float tile[32][33];
    const int n0 = blockIdx.x * 32, k0 = blockIdx.y * 32;
    const int r = threadIdx.x >> 3, c4 = (threadIdx.x & 7) * 4;
    float4 v = *(const float4*)&W[(size_t)(k0 + r) * N + n0 + c4];
    tile[r][c4] = v.x; tile[r][c4+1] = v.y; tile[r][c4+2] = v.z; tile[r][c4+3] = v.w;
    __syncthreads();
    ushort4 o = make_ushort4(tobf(tile[c4+0][r]), tobf(tile[c4+1][r]),
                             tobf(tile[c4+2][r]), tobf(tile[c4+3][r]));
    *(ushort4*)&WT[(size_t)(n0 + r) * K + k0 + c4] = o;
}

// ---------------- m97-style GEMM: A(MxK bf16) @ Bt(NxK bf16)^T + bias -> C --
__device__ __forceinline__ void store_out(u16* p, float v)  { *p = tobf(v); }
__device__ __forceinline__ void store_out(float* p, float v){ *p = v; }

template <typename OT>
__global__ __launch_bounds__(256) void gemm_bt(
    const u16* __restrict__ A, const u16* __restrict__ Bt,
    const float* __restrict__ bias, OT* __restrict__ C,
    int N, int K, float out_scale)
{
    __shared__ __align__(16) u16 As[128 * 32];
    __shared__ __align__(16) u16 Bs[128 * 32];
    const int t = threadIdx.x;
    const int w = t >> 6, l = t & 63;
    const int lane15 = l & 15, quad = l >> 4;
    const int m0 = blockIdx.y * 128, n0 = blockIdx.x * 128;
    const int wm = (w >> 1) * 64, wn = (w & 1) * 64;
    const int lr = l >> 2, lk = (l & 3) * 8;

    f32x4 acc[4][4] = {};

    for (int k0 = 0; k0 < K; k0 += 32) {
        __syncthreads();
        #pragma unroll
        for (int i = 0; i < 2; ++i) {
            const int chunk = w * 2 + i;
            gl_lds16(A  + (size_t)(m0 + chunk*16 + lr) * K + k0 + lk,
                     As + chunk * 512);
            gl_lds16(Bt + (size_t)(n0 + chunk*16 + lr) * K + k0 + lk,
                     Bs + chunk * 512);
        }
        __syncthreads();
        s16x8 af[4], bfr[4];
        #pragma unroll
        for (int i = 0; i < 4; ++i)
            af[i] = *(const s16x8*)&As[(wm + i*16 + lane15) * 32 + quad * 8];
        #pragma unroll
        for (int j = 0; j < 4; ++j)
            bfr[j] = *(const s16x8*)&Bs[(wn + j*16 + lane15) * 32 + quad * 8];
        #pragma unroll
        for (int i = 0; i < 4; ++i)
            #pragma unroll
            for (int j = 0; j < 4; ++j)
                acc[i][j] = __builtin_amdgcn_mfma_f32_16x16x32_bf16(
                    af[i], bfr[j], acc[i][j], 0, 0, 0);
    }
    #pragma unroll
    for (int j = 0; j < 4; ++j) {
        const int col = n0 + wn + j*16 + lane15;
        const float bv = bias[col];
        #pragma unroll
        for (int i = 0; i < 4; ++i)
            #pragma unroll
            for (int r = 0; r < 4; ++r) {
                const int row = m0 + wm + i*16 + quad*4 + r;
                store_out(C + (size_t)row * N + col, (acc[i][j][r] + bv) * out_scale);
            }
    }
}

// ---------------- V head transpose: kv[b,t,h*128+64+d] -> vt[(bh*64+d)*T+t] -
__global__ __launch_bounds__(256) void v_transpose(
    const u16* __restrict__ kvb, u16* __restrict__ vt)
{
    __shared__ __align__(16) u16 tile[64][72];
    const int t  = threadIdx.x;
    const int t0 = blockIdx.x * 64;
    const int bh = blockIdx.y;
    const int b = bh >> 4, h = bh & 15;
    const int r = t >> 2, c = (t & 3) * 16;
    const u16* g = kvb + (size_t)(b*SEQ + t0 + r) * (2*D_MODEL) + h*128 + 64 + c;
    *(uint4*)&tile[r][c]     = *(const uint4*)g;
    *(uint4*)&tile[r][c + 8] = *(const uint4*)(g + 8);
    __syncthreads();
    u16 buf[16];
    #pragma unroll
    for (int i = 0; i < 16; ++i) buf[i] = tile[c + i][r];
    u16* o = vt + (size_t)(bh*64 + r) * SEQ + t0 + c;
    *(uint4*)o       = *(uint4*)&buf[0];
    *(uint4*)(o + 8) = *(uint4*)&buf[8];
}

// ---------------- Transposed MFMA flash attention, async dbuf ----------------
// 4 waves x 32 q-rows (2 frag sets). K-tile 64, double-buffered via
// global_load_lds into unpadded half-tiles ([half][64 rows][32 u16] — 32-u16
// rows keep frag reads 2-way-conflict-free). Mask prefetched 1 iter ahead
// into regs, used as MFMA C-init. No-max softmax (bounded scores).
__global__ __launch_bounds__(256, 3) void attn_mfma(
    const u16* __restrict__ qb, const u16* __restrict__ kvb,
    const u16* __restrict__ vt, const u16* __restrict__ mp,
    u16* __restrict__ resb)
{
    // sm: Kbuf[2] @0/4096, Vbuf[2] @8192/12288, Ps @16384 (4*32*72)
    __shared__ __align__(16) u16 sm[4*4096 + 4*32*72];
    const int t = threadIdx.x;
    const int w = t >> 6, l = t & 63;
    const int lane15 = l & 15, quad = l >> 4;
    const int h  = blockIdx.x;
    const int q0 = blockIdx.y * QB;
    const int b  = blockIdx.z;
    const int bh = b * NH + h;
    const int lr4 = l >> 2, lc8 = (l & 3) * 8;

    // Q fragments for the wave's 2 q-sets (Q/8 pre-scaled)
    s16x8 aq0[2], aq1[2];
    #pragma unroll
    for (int s = 0; s < 2; ++s) {
        const u16* qrow = qb + (size_t)(b*SEQ + q0 + w*32 + s*16 + lane15) * D_MODEL + h*HEAD;
        aq0[s] = *(const s16x8*)(qrow + quad*8);
        aq1[s] = *(const s16x8*)(qrow + 32 + quad*8);
    }
    const u16* mrow[2];
    #pragma unroll
    for (int s = 0; s < 2; ++s)
        mrow[s] = mp + (((size_t)b*128 + (q0>>4) + w*2 + s) * 128) * 256 + (size_t)l*4;

    // async stage of K/V tiles for k-offset k0s into buffer bf
    auto stage = [&](int k0s, int bf) {
        #pragma unroll
        for (int i = 0; i < 2; ++i) {
            const int c = w*2 + i;
            const int hh = c & 1, rr = c >> 1;
            const u16* kg = kvb + (size_t)(b*SEQ + k0s + rr*16 + lr4) * (2*D_MODEL)
                                + h*128 + hh*32 + lc8;
            gl_lds16(kg, sm + bf*4096 + hh*2048 + rr*512);
            const u16* vg = vt + (size_t)(bh*64 + rr*16 + lr4) * SEQ
                               + k0s + hh*32 + lc8;
            gl_lds16(vg, sm + 8192 + bf*4096 + hh*2048 + rr*512);
        }
    };

    f32x4 o_acc[2][4] = {};
    float l_i[2] = {0.f, 0.f};
    ushort4 mreg[2][4];

    stage(0, 0);
    #pragma unroll
    for (int s = 0; s < 2; ++s)
        #pragma unroll
        for (int nt = 0; nt < 4; ++nt)
            mreg[s][nt] = *(const ushort4*)(mrow[s] + (size_t)nt * 256);

    u16* const Ps = sm + 16384;

    for (int it = 0; it < SEQ/64; ++it) {
        const int k0 = it * 64;
        const int bf = it & 1;
        __syncthreads();   // drains gl_lds + mask loads; syncs prev compute
        ushort4 mnxt[2][4];
        if (it + 1 < SEQ/64) {
            stage(k0 + 64, bf ^ 1);
            #pragma unroll
            for (int s = 0; s < 2; ++s)
                #pragma unroll
                for (int nt = 0; nt < 4; ++nt)
                    mnxt[s][nt] = *(const ushort4*)(mrow[s] + ((size_t)((k0+64)>>4) + nt) * 256);
        }

        // K fragments (shared by both q-sets)
        s16x8 kf[4][2];
        #pragma unroll
        for (int nt = 0; nt < 4; ++nt) {
            kf[nt][0] = *(const s16x8*)(sm + bf*4096 +        (nt*16 + lane15)*32 + quad*8);
            kf[nt][1] = *(const s16x8*)(sm + bf*4096 + 2048 + (nt*16 + lane15)*32 + quad*8);
        }

        #pragma unroll
        for (int s = 0; s < 2; ++s) {
            f32x4 sv[4];
            #pragma unroll
            for (int nt = 0; nt < 4; ++nt) {
                sv[nt][0] = frombf(mreg[s][nt].x); sv[nt][1] = frombf(mreg[s][nt].y);
                sv[nt][2] = frombf(mreg[s][nt].z); sv[nt][3] = frombf(mreg[s][nt].w);
                sv[nt] = __builtin_amdgcn_mfma_f32_16x16x32_bf16(kf[nt][0], aq0[s], sv[nt], 0, 0, 0);
                sv[nt] = __builtin_amdgcn_mfma_f32_16x16x32_bf16(kf[nt][1], aq1[s], sv[nt], 0, 0, 0);
            }
            float rs = 0.f;
            #pragma unroll
            for (int nt = 0; nt < 4; ++nt)
                #pragma unroll
                for (int r = 0; r < 4; ++r) {
                    float p = __expf(sv[nt][r]);
                    sv[nt][r] = p;
                    rs += p;
                }
            rs += __shfl_xor(rs, 16);
            rs += __shfl_xor(rs, 32);
            l_i[s] += rs;
            u16* prow = Ps + (w*32 + s*16 + lane15) * 72;
            #pragma unroll
            for (int nt = 0; nt < 4; ++nt) {
                uint2 pv = make_uint2(pack_bf2(sv[nt][0], sv[nt][1]),
                                      pack_bf2(sv[nt][2], sv[nt][3]));
                *(uint2*)&prow[nt*16 + quad*4] = pv;
            }
        }

        // PV: O^T += V^T . P^T
        #pragma unroll
        for (int s = 0; s < 2; ++s) {
            const u16* prow = Ps + (w*32 + s*16 + lane15) * 72;
            s16x8 pf0 = *(const s16x8*)&prow[quad*8];
            s16x8 pf1 = *(const s16x8*)&prow[32 + quad*8];
            #pragma unroll
            for (int dt = 0; dt < 4; ++dt) {
                s16x8 vf0 = *(const s16x8*)(sm + 8192 + bf*4096 +        (dt*16 + lane15)*32 + quad*8);
                s16x8 vf1 = *(const s16x8*)(sm + 8192 + bf*4096 + 2048 + (dt*16 + lane15)*32 + quad*8);
                o_acc[s][dt] = __builtin_amdgcn_mfma_f32_16x16x32_bf16(vf0, pf0, o_acc[s][dt], 0, 0, 0);
                o_acc[s][dt] = __builtin_amdgcn_mfma_f32_16x16x32_bf16(vf1, pf1, o_acc[s][dt], 0, 0, 0);
            }
        }

        if (it + 1 < SEQ/64) {
            #pragma unroll
            for (int s = 0; s < 2; ++s)
                #pragma unroll
                for (int nt = 0; nt < 4; ++nt)
                    mreg[s][nt] = mnxt[s][nt];
        }
    }

    // Epilogue: O^T (col=q, row=d) -> LDS transpose (reuse K/V bufs) -> store
    __syncthreads();
    #pragma unroll
    for (int s = 0; s < 2; ++s) {
        const float inv = 1.f / l_i[s];
        u16* orow = &sm[(w*32 + s*16 + lane15) * 72];
        #pragma unroll
        for (int dt = 0; dt < 4; ++dt) {
            uint2 ov = make_uint2(pack_bf2(o_acc[s][dt][0]*inv, o_acc[s][dt][1]*inv),
                                  pack_bf2(o_acc[s][dt][2]*inv, o_acc[s][dt][3]*inv));
            *(uint2*)&orow[dt*16 + quad*4] = ov;
        }
    }
    __syncthreads();
    {
        const int tr = t >> 1, tc = (t & 1) * 32;
        u16* o = resb + (size_t)(b*SEQ + q0 + tr) * D_MODEL + h*HEAD + tc;
        #pragma unroll
        for (int j = 0; j < 4; ++j)
            *(uint4*)(o + j*8) = *(const uint4*)&sm[tr*72 + tc + j*8];
    }
}

extern "C" void kernel_launch(void* const* d_in, const int* in_sizes, int n_in,
                              void* d_out, int out_size, void* d_ws, size_t ws_size,
                              hipStream_t stream) {
    const float* x_enc = (const float*)d_in[0];
    const float* x_dec = (const float*)d_in[1];
    const float* mask  = (const float*)d_in[2];
    const float* Wq    = (const float*)d_in[3];
    const float* bq    = (const float*)d_in[4];
    const float* Wkv   = (const float*)d_in[5];
    const float* bkv   = (const float*)d_in[6];
    const float* Wo    = (const float*)d_in[7];
    const float* bo    = (const float*)d_in[8];
    float* out = (float*)d_out;

    const int M = BATCH * SEQ;  // 8192
    u16* xe   = (u16*)d_ws;                       // 8192x1024 (16.8 MB)
    u16* xd   = xe   + (size_t)M * D_MODEL;       // 8192x1024 (16.8 MB)
    u16* wqT  = xd   + (size_t)M * D_MODEL;       // 1024x1024
    u16* wkvT = wqT  + (size_t)D_MODEL * D_MODEL; // 2048x1024
    u16* woT  = wkvT + (size_t)2*D_MODEL*D_MODEL; // 1024x1024
    u16* qbuf = woT  + (size_t)D_MODEL * D_MODEL; // 8192x1024 (holds Q/8)
    u16* kvb  = qbuf + (size_t)M * D_MODEL;       // 8192x2048
    u16* vtb  = kvb  + (size_t)M * 2 * D_MODEL;   // 64x64x2048
    u16* resb = vtb  + (size_t)BATCH*NH*HEAD*SEQ; // 8192x1024
    u16* mpk  = xe;   // mask C-frag buffer (33.6 MB) aliases xe+xd after GEMMs

    const int NX = M * D_MODEL;  // 8388608
    cast_bf16<<<NX/1024, 256, 0, stream>>>(x_enc, xe, NX);
    cast_bf16<<<NX/1024, 256, 0, stream>>>(x_dec, xd, NX);
    transpose_cast<<<dim3(D_MODEL/32, D_MODEL/32), 256, 0, stream>>>(Wq,  wqT,  D_MODEL, D_MODEL);
    transpose_cast<<<dim3(2*D_MODEL/32, D_MODEL/32), 256, 0, stream>>>(Wkv, wkvT, D_MODEL, 2*D_MODEL);
    transpose_cast<<<dim3(D_MODEL/32, D_MODEL/32), 256, 0, stream>>>(Wo,  woT,  D_MODEL, D_MODEL);

    gemm_bt<u16><<<dim3(2*D_MODEL/128, M/128), 256, 0, stream>>>(
        xe, wkvT, bkv, kvb, 2*D_MODEL, D_MODEL, 1.0f);
    gemm_bt<u16><<<dim3(D_MODEL/128, M/128), 256, 0, stream>>>(
        xd, wqT, bq, qbuf, D_MODEL, D_MODEL, 0.125f);   // fold 1/sqrt(HEAD)
    // xe/xd dead now; pack mask into their space
    mask_prep<<<(BATCH*128*128*64)/256, 256, 0, stream>>>(mask, mpk);
    v_transpose<<<dim3(SEQ/64, BATCH*NH), 256, 0, stream>>>(kvb, vtb);
    attn_mfma<<<dim3(NH, SEQ/QB, BATCH), 256, 0, stream>>>(
        qbuf, kvb, vtb, mpk, resb);
    gemm_bt<float><<<dim3(D_MODEL/128, M/128), 256, 0, stream>>>(
        resb, woT, bo, out, D_MODEL, D_MODEL, 1.0f);
}